// Round 1
// baseline (44.100 us; speedup 1.0000x reference)
//
#include <hip/hip_runtime.h>

#define NN 1024
#define FF 128
#define FP 64
#define NH 2

// ws layout (float offsets):
// UT: [H][FP][N]  @ 0        (HW1 + b, transposed [e][i])
// VT: [H][FP][N]  @ 131072   (HW2 transposed [e][j])
// H1: [H][N][FP]  @ 262144   (natural, no bias)
// H2: [H][N][FP]  @ 393216
// su: [H][N]      @ 524288   (= sum_e a_e*(HW1+b))
// sv: [H][N]      @ 526336   (= sum_e a_e*HW2)

__global__ __launch_bounds__(256) void kA(const float* __restrict__ X,
        const float* __restrict__ W1, const float* __restrict__ W2,
        const float* __restrict__ b, const float* __restrict__ a,
        float* __restrict__ ws) {
    int bx = blockIdx.x;
    int w  = bx >> 9;           // 0: W1 path, 1: W2 path
    int h  = (bx >> 8) & 1;
    int nt = bx & 255;
    int t  = threadIdx.x;
    int e  = t & 63;
    int n  = nt * 4 + (t >> 6);

    const float* Wp   = (w ? W2 : W1) + h * FF * FP + e;  // stride FP over f
    const float* Xrow = X + n * FF;                        // wave-uniform
    float acc = 0.f;
    #pragma unroll
    for (int f = 0; f < FF; f += 4) {
        float4 x = *(const float4*)(Xrow + f);
        acc += x.x * Wp[(f + 0) * FP];
        acc += x.y * Wp[(f + 1) * FP];
        acc += x.z * Wp[(f + 2) * FP];
        acc += x.w * Wp[(f + 3) * FP];
    }
    float be     = w ? 0.f : b[h * FP + e];
    float withb  = acc + be;
    float scaled = a[h * FP + e] * withb;

    float* Hnat = ws + (w ? 393216 : 262144);
    Hnat[(h * NN + n) * FP + e] = acc;
    float* Tr = ws + (w ? 131072 : 0);
    Tr[(h * FP + e) * NN + n] = withb;

    // wave-reduce 'scaled' over the 64 e-lanes -> su/sv
    float r = scaled;
    for (int off = 32; off; off >>= 1) r += __shfl_xor(r, off, 64);
    if (e == 0) {
        float* s = ws + (w ? 526336 : 524288);
        s[h * NN + n] = r;
    }
}

__global__ __launch_bounds__(256) void kB(const float* __restrict__ A,
        const float* __restrict__ a, const float* __restrict__ ws,
        float* __restrict__ attRaw) {
    int bx  = blockIdx.x;
    int h   = bx >> 9;
    int rem = bx & 511;
    int i0  = (rem >> 2) * 8;          // 128 i-tiles of 8
    int j   = (rem & 3) * 256 + threadIdx.x;

    const float* UT = ws + h * FP * NN;            // [e][i]
    const float* VT = ws + 131072 + h * FP * NN;   // [e][j]
    const float* ap = a + h * FP;

    float sv = ws[526336 + h * NN + j];
    float acc[8];
    #pragma unroll
    for (int ii = 0; ii < 8; ++ii) acc[ii] = 0.f;

    #pragma unroll 4
    for (int e = 0; e < FP; ++e) {
        float v = VT[e * NN + j];              // coalesced vector load
        const float* up = UT + e * NN + i0;    // wave-uniform -> s_load
        float ae = ap[e];                      // wave-uniform
        #pragma unroll
        for (int ii = 0; ii < 8; ++ii) {
            float tv = v + up[ii];
            acc[ii] += ae * fabsf(tv);
        }
    }

    const float* sup = ws + 524288 + h * NN + i0;
    #pragma unroll
    for (int ii = 0; ii < 8; ++ii) {
        int i = i0 + ii;
        float logit = 0.6f * (sup[ii] + sv) + 0.4f * acc[ii];
        float Aij   = A[i * NN + j];           // coalesced
        float sig   = 1.f / (1.f + __expf(-logit));
        attRaw[(h * NN + i) * NN + j] = (Aij != 0.f) ? sig : 0.f;
    }
}

__global__ __launch_bounds__(256) void kC(const float* __restrict__ ws,
        float* __restrict__ out, float* __restrict__ att) {
    __shared__ int   s_cnt;
    __shared__ int   s_idx[1024];
    __shared__ float s_val[1024];
    __shared__ float s_red[4];
    __shared__ float s_part[256];

    int bx  = blockIdx.x;
    int h   = bx >> 10;
    int i   = bx & 1023;
    int tid = threadIdx.x;
    if (tid == 0) s_cnt = 0;
    __syncthreads();

    float* row = att + (h * NN + i) * NN;
    float4 r4  = ((const float4*)row)[tid];
    float  s   = r4.x + r4.y + r4.z + r4.w;

    float vals[4] = {r4.x, r4.y, r4.z, r4.w};
    #pragma unroll
    for (int k = 0; k < 4; ++k) {
        if (vals[k] != 0.f) {
            int p = atomicAdd(&s_cnt, 1);
            s_idx[p] = tid * 4 + k;
            s_val[p] = vals[k];
        }
    }

    for (int off = 32; off; off >>= 1) s += __shfl_xor(s, off, 64);
    int wave = tid >> 6;
    if ((tid & 63) == 0) s_red[wave] = s;
    __syncthreads();

    float S   = s_red[0] + s_red[1] + s_red[2] + s_red[3];
    float inv = 1.f / (1.f + S);

    // in-place normalize (row is only re-read via the LDS list from here on)
    float4 o4;
    o4.x = r4.x * inv; o4.y = r4.y * inv; o4.z = r4.z * inv; o4.w = r4.w * inv;
    ((float4*)row)[tid] = o4;

    // sparse aggregation: acc_e = sum_j raw_att[i,j] * HW2[h,j,e]
    int e = tid & 63;
    const float* H2p = ws + 393216 + h * NN * FP;
    float acc = 0.f;
    int cnt = s_cnt;
    for (int k = wave; k < cnt; k += 4) {
        acc += s_val[k] * H2p[s_idx[k] * FP + e];   // broadcast LDS, coalesced H2
    }
    s_part[tid] = acc;
    __syncthreads();

    if (tid < 64) {
        float tot = s_part[e] + s_part[64 + e] + s_part[128 + e] + s_part[192 + e];
        float h1  = ws[262144 + (h * NN + i) * FP + e];
        float val = inv * (h1 + tot);
        out[i * (NH * FP) + h * FP + e] = fmaxf(val, 0.f);
    }
}

extern "C" void kernel_launch(void* const* d_in, const int* in_sizes, int n_in,
                              void* d_out, int out_size, void* d_ws, size_t ws_size,
                              hipStream_t stream) {
    const float* X  = (const float*)d_in[0];
    const float* A  = (const float*)d_in[1];
    const float* W1 = (const float*)d_in[2];
    const float* W2 = (const float*)d_in[3];
    const float* b  = (const float*)d_in[4];
    const float* a  = (const float*)d_in[5];

    float* out = (float*)d_out;
    float* att = out + NN * NH * FP;   // 131072
    float* ws  = (float*)d_ws;

    kA<<<1024, 256, 0, stream>>>(X, W1, W2, b, a, ws);
    kB<<<1024, 256, 0, stream>>>(A, a, ws, att);
    kC<<<2048, 256, 0, stream>>>(ws, out, att);
}